// Round 15
// baseline (168.961 us; speedup 1.0000x reference)
//
#include <hip/hip_runtime.h>
#include <hip/hip_bf16.h>

#define NB 2
#define NS 2048
#define ND 1024
#define NH 16
#define NDK 64
#define GK 1024  // GEMM K (= ND)

using bf16_t = __hip_bfloat16;
typedef __attribute__((ext_vector_type(8))) short bf16x8;
typedef __attribute__((ext_vector_type(4))) float f32x4;
typedef unsigned short u16;
typedef unsigned int u32;

#define SC_LOG2E 0.1803368801f  // 0.125 * log2(e)

static __device__ __forceinline__ u16 f2bf(float f) {
    __hip_bfloat16 h = __float2bfloat16(f);
    return *reinterpret_cast<u16*>(&h);
}

// packed f32x2 -> bf16x2 (RNE), single instruction
static __device__ __forceinline__ u32 cvtpk2(float a, float b) {
    u32 r;
    asm("v_cvt_pk_bf16_f32 %0, %1, %2" : "=v"(r) : "v"(a), "v"(b));
    return r;
}

// async global->LDS DMA, 16B per lane. LDS dest = wave-uniform base + lane*16.
#define GLDS16(gp, lp)                                                                    \
    __builtin_amdgcn_global_load_lds((const __attribute__((address_space(1))) void*)(gp), \
                                     (__attribute__((address_space(3))) void*)(lp), 16, 0, 0)

// ---------------------------------------------------------------------------
// Kernel 0: fused prep — grid (4096, 5):
//   y=0..2 : q/k/v fp32 -> bf16
//   y=3    : Wq/Wk/Wv/Wo fp32 -> bf16 (x>>10 selects weight)
//   y=4    : combined mask  comb = (am==1) ? -1 : SC_LOG2E*(1 + 0.5*cm)
// ---------------------------------------------------------------------------
struct PrepArgs {
    const float* qkv_s[3];
    u16* qkv_d[3];
    const float* w_s[4];
    u16* w_d[4];
    const int* am;
    const float* cm;
    float* comb;
};

__global__ __launch_bounds__(256) void prep_kernel(PrepArgs a) {
    const int x = blockIdx.x, y = blockIdx.y, tid = threadIdx.x;
    if (y < 3) {
        int i = x * 256 + tid;
        float4 v = reinterpret_cast<const float4*>(a.qkv_s[y])[i];
        ushort4 o;
        o.x = f2bf(v.x); o.y = f2bf(v.y); o.z = f2bf(v.z); o.w = f2bf(v.w);
        reinterpret_cast<ushort4*>(a.qkv_d[y])[i] = o;
    } else if (y == 3) {
        int w = x >> 10;
        int i = (x & 1023) * 256 + tid;
        float4 v = reinterpret_cast<const float4*>(a.w_s[w])[i];
        ushort4 o;
        o.x = f2bf(v.x); o.y = f2bf(v.y); o.z = f2bf(v.z); o.w = f2bf(v.w);
        reinterpret_cast<ushort4*>(a.w_d[w])[i] = o;
    } else {
        int i = (x * 256 + tid) * 4;
        int4 m = *reinterpret_cast<const int4*>(a.am + i);
        float4 c = *reinterpret_cast<const float4*>(a.cm + i);
        float4 r;
        r.x = (m.x == 1) ? -1.0f : fmaf(0.5f * SC_LOG2E, c.x, SC_LOG2E);
        r.y = (m.y == 1) ? -1.0f : fmaf(0.5f * SC_LOG2E, c.y, SC_LOG2E);
        r.z = (m.z == 1) ? -1.0f : fmaf(0.5f * SC_LOG2E, c.z, SC_LOG2E);
        r.w = (m.w == 1) ? -1.0f : fmaf(0.5f * SC_LOG2E, c.w, SC_LOG2E);
        *reinterpret_cast<float4*>(a.comb + i) = r;
    }
}

// ---------------------------------------------------------------------------
// Kernel 2: m97-style bf16 MFMA GEMM with global_load_lds staging + T1 XCD
// swizzle. C[m][n] = sum_k A[m][k]*B[n][k] + bias[n]. BM=128, BK=32, dbuf.
// mode 0: fp32 [M][ND]. mode 1: bf16 [B,H,S,DK]. mode 2: bf16 [B,H,DK,S].
// ---------------------------------------------------------------------------
struct MMArgs {
    const u16* A;
    const u16* W;
    const float* bias;
    void* out;
    int mode;
};

template <int BN>
__global__ __launch_bounds__(256) void mm_glds(MMArgs g0, MMArgs g1, MMArgs g2) {
    const MMArgs ga = (blockIdx.z == 0) ? g0 : (blockIdx.z == 1) ? g1 : g2;
    constexpr int BM = 128, BK = 32;
    constexpr int JN = BN / 32;
    __shared__ __align__(16) u16 As[2][BM * BK];
    __shared__ __align__(16) u16 Bs[2][BN * BK];

    const int tid = threadIdx.x;
    const int lane = tid & 63;
    const int w = tid >> 6;
    const int wm = w >> 1, wn = w & 1;
    const int fr = lane & 15, fg = lane >> 4;

    // T1: XCD-aware remap (per z-slice; nxy % 8 == 0 so the map is bijective)
    const int nxy = gridDim.x * gridDim.y;
    const int flat0 = blockIdx.y * gridDim.x + blockIdx.x;
    const int chunk = nxy >> 3;
    const int flat = (flat0 & 7) * chunk + (flat0 >> 3);
    const int bxi = flat % gridDim.x, byi = flat / gridDim.x;
    const int bm0 = byi * BM, bn0 = bxi * BN;

    const u16* agp = ga.A + (size_t)(bm0 + w * 32 + (lane >> 2)) * GK + (lane & 3) * 8;
    const u16* bgp = ga.W +
                     (size_t)(bn0 + w * (BN == 128 ? 32 : 16) + (lane >> 2)) * GK +
                     (lane & 3) * 8;

    f32x4 acc[4][JN];
    const f32x4 z4 = {0.f, 0.f, 0.f, 0.f};
#pragma unroll
    for (int i = 0; i < 4; ++i)
#pragma unroll
        for (int j = 0; j < JN; ++j) acc[i][j] = z4;

    {
        u16* la = &As[0][w * 1024];
        u16* lb = &Bs[0][w * (BN == 128 ? 1024 : 512)];
        GLDS16(agp, la);
        GLDS16(agp + 16 * GK, la + 512);
        if (BN == 128) {
            GLDS16(bgp, lb);
            GLDS16(bgp + 16 * GK, lb + 512);
        } else {
            GLDS16(bgp, lb);
        }
    }
    __syncthreads();

    int cur = 0;
    for (int kt = 0; kt < GK / BK; ++kt) {
        if (kt + 1 < GK / BK) {
            const int ko = (kt + 1) * BK;
            u16* la = &As[cur ^ 1][w * 1024];
            u16* lb = &Bs[cur ^ 1][w * (BN == 128 ? 1024 : 512)];
            GLDS16(agp + ko, la);
            GLDS16(agp + ko + 16 * GK, la + 512);
            if (BN == 128) {
                GLDS16(bgp + ko, lb);
                GLDS16(bgp + ko + 16 * GK, lb + 512);
            } else {
                GLDS16(bgp + ko, lb);
            }
        }
        bf16x8 af[4], bfr[JN];
#pragma unroll
        for (int i = 0; i < 4; ++i)
            af[i] = *(const bf16x8*)&As[cur][(wm * 64 + i * 16 + fr) * BK + fg * 8];
#pragma unroll
        for (int j = 0; j < JN; ++j)
            bfr[j] = *(const bf16x8*)&Bs[cur][(wn * (BN / 2) + j * 16 + fr) * BK + fg * 8];
#pragma unroll
        for (int i = 0; i < 4; ++i)
#pragma unroll
            for (int j = 0; j < JN; ++j)
                acc[i][j] = __builtin_amdgcn_mfma_f32_16x16x32_bf16(af[i], bfr[j], acc[i][j],
                                                                    0, 0, 0);
        __syncthreads();
        cur ^= 1;
    }

#pragma unroll
    for (int j = 0; j < JN; ++j) {
        const int col = bn0 + wn * (BN / 2) + j * 16 + fr;
        const float bv_ = ga.bias[col];
        if (ga.mode == 2) {
            const int h_ = col >> 6, dk = col & (NDK - 1);
#pragma unroll
            for (int i = 0; i < 4; ++i) {
                const int row0 = bm0 + wm * 64 + i * 16 + fg * 4;
                const int b_ = row0 >> 11, s_ = row0 & (NS - 1);
                uint2 pw;
                pw.x = cvtpk2(acc[i][j][0] + bv_, acc[i][j][1] + bv_);
                pw.y = cvtpk2(acc[i][j][2] + bv_, acc[i][j][3] + bv_);
                *(uint2*)((u16*)ga.out +
                          (((size_t)(b_ * NH + h_)) * NDK + dk) * NS + s_) = pw;
            }
        } else {
#pragma unroll
            for (int i = 0; i < 4; ++i) {
#pragma unroll
                for (int r = 0; r < 4; ++r) {
                    const int row = bm0 + wm * 64 + i * 16 + fg * 4 + r;
                    const float val = acc[i][j][r] + bv_;
                    if (ga.mode == 1) {
                        const int b_ = row >> 11, s_ = row & (NS - 1);
                        const int h_ = col >> 6, dk = col & (NDK - 1);
                        ((bf16_t*)ga.out)[(((size_t)(b_ * NH + h_)) * NS + s_) * NDK + dk] =
                            __float2bfloat16(val);
                    } else {
                        ((float*)ga.out)[(size_t)row * ND + col] = val;
                    }
                }
            }
        }
    }
}

// ---------------------------------------------------------------------------
// Kernel 3: MFMA flash attention — KVBLK=32, QUAD-buffered K/V, counted-vmcnt
// pipeline (T3+T4). Per phase: load comb(t+1)->regs, issue 2 GLDS for tile
// t+3, QK(t), exp/P, lgkmcnt fence, PV(t), s_waitcnt vmcnt(6) (retires
// K/V(t+1)+comb(t); K/V(t+2), t+3, comb(t+1) stay IN FLIGHT across the
// barrier), raw s_barrier. Loop unrolled x4 -> all koff constants.
// LDS (36864 B): K bufs [0,16384) 4x4096 (32 rows x 128B, row&7-XOR 16B
// blocks); V bufs [16384,32768) 4x4096 (64 rows x 64B, row&3-XOR 16B slots);
// Pt [32768,36864) per-warp 16 rows x 64B, slot-XOR px=(qc>>1)&3.
// ---------------------------------------------------------------------------
__global__ __launch_bounds__(256) void flash_mfma(const u16* __restrict__ Qh,
                                                  const u16* __restrict__ Kh,
                                                  const u16* __restrict__ VhT,
                                                  const float* __restrict__ comb,
                                                  float* __restrict__ attnOut,
                                                  u16* __restrict__ concatOut) {
    __shared__ __align__(16) char smem[36864];

    const int tid = threadIdx.x;
    const int w = tid >> 6;
    const int lane = tid & 63;
    const int qc = lane & 15;
    const int g = lane >> 4;
    const int bh = blockIdx.y;
    const int b_ = bh >> 4, h_ = bh & 15;
    const int qw = blockIdx.x * 64 + w * 16;

    const size_t bhoff = (size_t)bh * NS * NDK;

    // swizzle decomposition
    const u32 kxl = qc & 3;
    const u32 kx2 = (qc >> 2) & 1;
    const u32 px = (qc >> 1) & 3;

    // ---- staging sources (per-lane, pre-swizzled) ----
    const int ksr = lane >> 3;                 // K: 8 rows/wave
    const int ksb = (lane & 7) ^ ksr;          // K 16B-block swizzle (row&7)
    const u16* kgn = Kh + bhoff + (size_t)(w * 8 + ksr) * NDK + ksb * 8;
    const int vsr = lane >> 2;                 // V: 16 rows/wave
    const int vsb = (lane & 3) ^ (vsr & 3);    // V 16B-slot swizzle (row&3)
    const u16* vgn = VhT + bhoff + (size_t)(w * 16 + vsr) * NS + vsb * 8;
    char* ksm = smem + w * 1024;               // + bufoff (0/4096/8192/12288)
    char* vsm = smem + 16384 + w * 1024;

    // ---- Q fragments (uniform kc pairing — MFMA k-axis is cross-lane) ----
    bf16x8 qf0, qf1;
    {
        const u16* qp = Qh + bhoff + (size_t)(qw + qc) * NDK + g * 8;
        qf0 = *(const bf16x8*)(qp);       // dk 0..31
        qf1 = *(const bf16x8*)(qp + 32);  // dk 32..63
    }

    bf16x8 vones;
#pragma unroll
    for (int j = 0; j < 8; ++j) vones[j] = (short)0x3F80;

    const f32x4 z4 = {0.f, 0.f, 0.f, 0.f};
    f32x4 o[4];
    o[0] = o[1] = o[2] = o[3] = z4;
    f32x4 o_l = z4;

    // ---- LDS read bases (kernel-constant; + KOFF immediates) ----
    const char* kb0 = smem + qc * 128 + ((g ^ kxl) << 4) + (kx2 << 6);        // kc=0
    const char* kb1 = smem + qc * 128 + ((g ^ kxl) << 4) + ((kx2 ^ 1) << 6);  // kc=1
    const char* vb = smem + 16384 + qc * 64 + ((g ^ kxl) << 4);
    char* ptrow = smem + 32768 + w * 1024 + qc * 64;
    char* pwb0 = ptrow + ((((g >> 1) ^ px) & 3) << 4) + ((g & 1) << 3);        // ks=0
    char* pwb1 = ptrow + (((((g >> 1) | 2) ^ px) & 3) << 4) + ((g & 1) << 3);  // ks=1
    const char* prd = ptrow + (((g ^ px) & 3) << 4);

    // ---- comb running pointer (row + g*4 folded in; +16 floats for ks=1) ----
    const float* cbp = comb + (size_t)(qw + qc) * NS + g * 4;

    float4 cX0, cX1, cY0, cY1;

    // ---- prologue: comb(0); stage tiles 0,1,2 into bufs 0,1,2 ----
    cX0 = *(const float4*)(cbp);
    cX1 = *(const float4*)(cbp + 16);
    cbp += 32;
    GLDS16(kgn, ksm);
    GLDS16(vgn, vsm);
    kgn += 32 * NDK; vgn += 32;
    GLDS16(kgn, ksm + 4096);
    GLDS16(vgn, vsm + 4096);
    kgn += 32 * NDK; vgn += 32;
    GLDS16(kgn, ksm + 8192);
    GLDS16(vgn, vsm + 8192);
    kgn += 32 * NDK; vgn += 32;
    asm volatile("s_waitcnt vmcnt(4)" ::: "memory");  // tile-0 loads done
    __builtin_amdgcn_s_barrier();
    asm volatile("" ::: "memory");

#define FL_PHASE(KOFF, KOFFW, CC0, CC1, CN0, CN1)                                          \
    {                                                                                      \
        CN0 = *(const float4*)(cbp);                                                       \
        CN1 = *(const float4*)(cbp + 16);                                                  \
        cbp += 32;                                                                         \
        GLDS16(kgn, ksm + (KOFFW));                                                        \
        GLDS16(vgn, vsm + (KOFFW));                                                        \
        kgn += 32 * NDK;                                                                   \
        vgn += 32;                                                                         \
        f32x4 s0 = z4, s1 = z4;                                                            \
        {                                                                                  \
            bf16x8 a0 = *(const bf16x8*)(kb0 + (KOFF));                                    \
            bf16x8 a1 = *(const bf16x8*)(kb1 + (KOFF));                                    \
            s0 = __builtin_amdgcn_mfma_f32_16x16x32_bf16(a0, qf0, s0, 0, 0, 0);            \
            s0 = __builtin_amdgcn_mfma_f32_16x16x32_bf16(a1, qf1, s0, 0, 0, 0);            \
            bf16x8 b0 = *(const bf16x8*)(kb0 + (KOFF) + 2048);                             \
            bf16x8 b1 = *(const bf16x8*)(kb1 + (KOFF) + 2048);                             \
            s1 = __builtin_amdgcn_mfma_f32_16x16x32_bf16(b0, qf0, s1, 0, 0, 0);            \
            s1 = __builtin_amdgcn_mfma_f32_16x16x32_bf16(b1, qf1, s1, 0, 0, 0);            \
        }                                                                                  \
        {                                                                                  \
            float p0 = __builtin_amdgcn_exp2f(s0[0] * (CC0).x);                            \
            float p1 = __builtin_amdgcn_exp2f(s0[1] * (CC0).y);                            \
            float p2 = __builtin_amdgcn_exp2f(s0[2] * (CC0).z);                            \
            float p3 = __builtin_amdgcn_exp2f(s0[3] * (CC0).w);                            \
            p0 = ((CC0).x < 0.f) ? 0.f : p0;                                               \
            p1 = ((CC0).y < 0.f) ? 0.f : p1;                                               \
            p2 = ((CC0).z < 0.f) ? 0.f : p2;                                               \
            p3 = ((CC0).w < 0.f) ? 0.f : p3;                                               \
            uint2 pwa;                                                                     \
            pwa.x = cvtpk2(p0, p1);                                                        \
            pwa.y = cvtpk2(p2, p3);                                                        \
            *(uint2*)(pwb0) = pwa;                                                         \
            float q0 = __builtin_amdgcn_exp2f(s1[0] * (CC1).x);                            \
            float q1 = __builtin_amdgcn_exp2f(s1[1] * (CC1).y);                            \
            float q2 = __builtin_amdgcn_exp2f(s1[2] * (CC1).z);                            \
            float q3 = __builtin_amdgcn_exp2f(s1[3] * (CC1).w);                            \
            q0 = ((CC1).x < 0.f) ? 0.f : q0;                                               \
            q1 = ((CC1).y < 0.f) ? 0.f : q1;                                               \
            q2 = ((CC1).z < 0.f) ? 0.f : q2;                                               \
            q3 = ((CC1).w < 0.f) ? 0.f : q3;                                               \
            uint2 pwbv;                                                                    \
            pwbv.x = cvtpk2(q0, q1);                                                       \
            pwbv.y = cvtpk2(q2, q3);                                                       \
            *(uint2*)(pwb1) = pwbv;                                                        \
        }                                                                                  \
        asm volatile("s_waitcnt lgkmcnt(0)" ::: "memory");                                 \
        __builtin_amdgcn_sched_barrier(0);                                                 \
        {                                                                                  \
            bf16x8 pf = *(const bf16x8*)(prd);                                             \
            o_l = __builtin_amdgcn_mfma_f32_16x16x32_bf16(pf, vones, o_l, 0, 0, 0);        \
            bf16x8 v0 = *(const bf16x8*)(vb + (KOFF));                                     \
            o[0] = __builtin_amdgcn_mfma_f32_16x16x32_bf16(pf, v0, o[0], 0, 0, 0);         \
            bf16x8 v1 = *(const bf16x8*)(vb + (KOFF) + 1024);                              \
            o[1] = __builtin_amdgcn_mfma_f32_16x16x32_bf16(pf, v1, o[1], 0, 0, 0);         \
            bf16x8 v2 = *(const bf16x8*)(vb + (KOFF) + 2048);                              \
            o[2] = __builtin_amdgcn_mfma_f32_16x16x32_bf16(pf, v2, o[2], 0, 0, 0);         \
            bf16x8 v3 = *(const bf16x8*)(vb + (KOFF) + 3072);                              \
            o[3] = __builtin_amdgcn_mfma_f32_16x16x32_bf16(pf, v3, o[3], 0, 0, 0);         \
        }                                                                                  \
        asm volatile("s_waitcnt vmcnt(6)" ::: "memory");                                   \
        __builtin_amdgcn_s_barrier();                                                      \
        asm volatile("" ::: "memory");                                                     \
    }

    for (int it = 0; it < 16; ++it) {
        FL_PHASE(0, 12288, cX0, cX1, cY0, cY1)
        FL_PHASE(4096, 0, cY0, cY1, cX0, cX1)
        FL_PHASE(8192, 4096, cX0, cX1, cY0, cY1)
        FL_PHASE(12288, 8192, cY0, cY1, cX0, cX1)
    }
#undef FL_PHASE

    // ---- normalize + store (attn fp32 [B,H,S,DK], concat bf16 [B,S,D]) ----
    float inv[4];
#pragma unroll
    for (int r = 0; r < 4; ++r) inv[r] = 1.0f / o_l[r];

#pragma unroll
    for (int dsub = 0; dsub < 4; ++dsub) {
#pragma unroll
        for (int r = 0; r < 4; ++r) {
            const float val = o[dsub][r] * inv[r];
            const int qg = qw + g * 4 + r;
            const int d = dsub * 16 + qc;
            attnOut[bhoff + (size_t)qg * NDK + d] = val;
            concatOut[((size_t)b_ * NS + qg) * ND + h_ * NDK + d] = f2bf(val);
        }
    }
}

// ---------------------------------------------------------------------------
extern "C" void kernel_launch(void* const* d_in, const int* in_sizes, int n_in,
                              void* d_out, int out_size, void* d_ws, size_t ws_size,
                              hipStream_t stream) {
    const float* q = (const float*)d_in[0];
    const float* k = (const float*)d_in[1];
    const float* v = (const float*)d_in[2];
    const int* am = (const int*)d_in[3];
    const float* cm = (const float*)d_in[4];
    const float* Wq = (const float*)d_in[5];
    const float* bq = (const float*)d_in[6];
    const float* Wk = (const float*)d_in[7];
    const float* bk = (const float*)d_in[8];
    const float* Wv = (const float*)d_in[9];
    const float* bv = (const float*)d_in[10];
    const float* Wo = (const float*)d_in[11];
    const float* bo = (const float*)d_in[12];

    float* out = (float*)d_out;                    // [B,S,D] fp32
    float* attn_out = out + (size_t)NB * NS * ND;  // [B,H,S,DK] fp32

    char* p = (char*)d_ws;
    float* CB = (float*)p;  p += (size_t)NS * NS * 4;
    u16* qb = (u16*)p;      p += (size_t)NB * NS * ND * 2;
    u16* kb_ = (u16*)p;     p += (size_t)NB * NS * ND * 2;
    u16* vb_ = (u16*)p;     p += (size_t)NB * NS * ND * 2;
    u16* Wqb = (u16*)p;     p += (size_t)ND * ND * 2;
    u16* Wkb = (u16*)p;     p += (size_t)ND * ND * 2;
    u16* Wvb = (u16*)p;     p += (size_t)ND * ND * 2;
    u16* Wob = (u16*)p;     p += (size_t)ND * ND * 2;
    u16* Qh = (u16*)p;      p += (size_t)NB * NS * ND * 2;
    u16* Kh = (u16*)p;      p += (size_t)NB * NS * ND * 2;
    u16* VhT = (u16*)p;     p += (size_t)NB * NS * ND * 2;
    u16* CCb = (u16*)p;     p += (size_t)NB * NS * ND * 2;

    PrepArgs pa;
    pa.qkv_s[0] = q;  pa.qkv_d[0] = qb;
    pa.qkv_s[1] = k;  pa.qkv_d[1] = kb_;
    pa.qkv_s[2] = v;  pa.qkv_d[2] = vb_;
    pa.w_s[0] = Wq;   pa.w_d[0] = Wqb;
    pa.w_s[1] = Wk;   pa.w_d[1] = Wkb;
    pa.w_s[2] = Wv;   pa.w_d[2] = Wvb;
    pa.w_s[3] = Wo;   pa.w_d[3] = Wob;
    pa.am = am;
    pa.cm = cm;
    pa.comb = CB;
    hipLaunchKernelGGL(prep_kernel, dim3(4096, 5), dim3(256), 0, stream, pa);

    MMArgs mq = {qb, Wqb, bq, (void*)Qh, 1};
    MMArgs mk = {kb_, Wkb, bk, (void*)Kh, 1};
    MMArgs mv = {vb_, Wvb, bv, (void*)VhT, 2};
    hipLaunchKernelGGL((mm_glds<128>), dim3(ND / 128, 4096 / 128, 3), dim3(256), 0, stream,
                       mq, mk, mv);

    hipLaunchKernelGGL(flash_mfma, dim3(NS / 64, NB * NH), dim3(256), 0, stream, Qh, Kh, VhT,
                       CB, attn_out, CCb);

    MMArgs mo = {CCb, Wob, bo, (void*)out, 0};
    hipLaunchKernelGGL((mm_glds<64>), dim3(ND / 64, 4096 / 128, 1), dim3(256), 0, stream,
                       mo, mo, mo);
}

// Round 16
// 158.611 us; speedup vs baseline: 1.0653x; 1.0653x over previous
//
#include <hip/hip_runtime.h>
#include <hip/hip_bf16.h>

#define NB 2
#define NS 2048
#define ND 1024
#define NH 16
#define NDK 64
#define GK 1024  // GEMM K (= ND)

using bf16_t = __hip_bfloat16;
typedef __attribute__((ext_vector_type(8))) short bf16x8;
typedef __attribute__((ext_vector_type(4))) float f32x4;
typedef unsigned short u16;
typedef unsigned int u32;

#define SC_LOG2E 0.1803368801f  // 0.125 * log2(e)

static __device__ __forceinline__ u16 f2bf(float f) {
    __hip_bfloat16 h = __float2bfloat16(f);
    return *reinterpret_cast<u16*>(&h);
}

// packed f32x2 -> bf16x2 (RNE), single instruction; a -> low16, b -> high16
static __device__ __forceinline__ u32 cvtpk2(float a, float b) {
    u32 r;
    asm("v_cvt_pk_bf16_f32 %0, %1, %2" : "=v"(r) : "v"(a), "v"(b));
    return r;
}

// async global->LDS DMA, 16B per lane. LDS dest = wave-uniform base + lane*16.
#define GLDS16(gp, lp)                                                                    \
    __builtin_amdgcn_global_load_lds((const __attribute__((address_space(1))) void*)(gp), \
                                     (__attribute__((address_space(3))) void*)(lp), 16, 0, 0)

// ---------------------------------------------------------------------------
// Kernel 0: prep — grid (4096, 2):
//   y=0 : Wq/Wk/Wv/Wo fp32 -> bf16 (x>>10 selects weight)
//   y=1 : combined mask  comb = (am==1) ? -1 : SC_LOG2E*(1 + 0.5*cm)
// (q/k/v conversion now fused into the QKV GEMM A-staging.)
// ---------------------------------------------------------------------------
struct PrepArgs {
    const float* w_s[4];
    u16* w_d[4];
    const int* am;
    const float* cm;
    float* comb;
};

__global__ __launch_bounds__(256) void prep_kernel(PrepArgs a) {
    const int x = blockIdx.x, y = blockIdx.y, tid = threadIdx.x;
    if (y == 0) {
        int w = x >> 10;
        int i = (x & 1023) * 256 + tid;
        float4 v = reinterpret_cast<const float4*>(a.w_s[w])[i];
        ushort4 o;
        o.x = f2bf(v.x); o.y = f2bf(v.y); o.z = f2bf(v.z); o.w = f2bf(v.w);
        reinterpret_cast<ushort4*>(a.w_d[w])[i] = o;
    } else {
        int i = (x * 256 + tid) * 4;
        int4 m = *reinterpret_cast<const int4*>(a.am + i);
        float4 c = *reinterpret_cast<const float4*>(a.cm + i);
        float4 r;
        r.x = (m.x == 1) ? -1.0f : fmaf(0.5f * SC_LOG2E, c.x, SC_LOG2E);
        r.y = (m.y == 1) ? -1.0f : fmaf(0.5f * SC_LOG2E, c.y, SC_LOG2E);
        r.z = (m.z == 1) ? -1.0f : fmaf(0.5f * SC_LOG2E, c.z, SC_LOG2E);
        r.w = (m.w == 1) ? -1.0f : fmaf(0.5f * SC_LOG2E, c.w, SC_LOG2E);
        *reinterpret_cast<float4*>(a.comb + i) = r;
    }
}

// ---------------------------------------------------------------------------
// Kernel 2: bf16 MFMA GEMM, T1 XCD swizzle. C = A@W^T + bias.
// BM=128, BK=32, dbuf LDS. B (weights, bf16) staged via global_load_lds.
// AF32=1: A is fp32 — staged global->regs->cvt_pk(RNE)->ds_write (conversion
// fused; identical rounding to the old prep pass). AF32=0: A bf16 via DMA.
// mode 0: fp32 [M][ND]. mode 1: bf16 [B,H,S,DK]. mode 2: bf16 [B,H,DK,S].
// ---------------------------------------------------------------------------
struct MMArgs {
    const void* A;
    const u16* W;
    const float* bias;
    void* out;
    int mode;
};

template <int BN, int AF32>
__global__ __launch_bounds__(256) void mm_glds(MMArgs g0, MMArgs g1, MMArgs g2) {
    const MMArgs ga = (blockIdx.z == 0) ? g0 : (blockIdx.z == 1) ? g1 : g2;
    constexpr int BM = 128, BK = 32;
    constexpr int JN = BN / 32;
    __shared__ __align__(16) u16 As[2][BM * BK];
    __shared__ __align__(16) u16 Bs[2][BN * BK];

    const int tid = threadIdx.x;
    const int lane = tid & 63;
    const int w = tid >> 6;
    const int wm = w >> 1, wn = w & 1;
    const int fr = lane & 15, fg = lane >> 4;

    // T1: XCD-aware remap (per z-slice; nxy % 8 == 0 so the map is bijective)
    const int nxy = gridDim.x * gridDim.y;
    const int flat0 = blockIdx.y * gridDim.x + blockIdx.x;
    const int chunk = nxy >> 3;
    const int flat = (flat0 & 7) * chunk + (flat0 >> 3);
    const int bxi = flat % gridDim.x, byi = flat / gridDim.x;
    const int bm0 = byi * BM, bn0 = bxi * BN;

    const int arow = bm0 + w * 32 + (lane >> 2);
    const int acol = (lane & 3) * 8;
    const u16* agp = (const u16*)ga.A + (size_t)arow * GK + acol;     // AF32=0
    const float* agp32 = (const float*)ga.A + (size_t)arow * GK + acol;  // AF32=1
    const u16* bgp = ga.W +
                     (size_t)(bn0 + w * (BN == 128 ? 32 : 16) + (lane >> 2)) * GK +
                     (lane & 3) * 8;

    // manual A-write slot (u16 index): same layout the DMA would produce
    u16* lwa0 = &As[0][w * 1024 + lane * 8];
    u16* lwa1 = &As[1][w * 1024 + lane * 8];

    f32x4 acc[4][JN];
    const f32x4 z4 = {0.f, 0.f, 0.f, 0.f};
#pragma unroll
    for (int i = 0; i < 4; ++i)
#pragma unroll
        for (int j = 0; j < JN; ++j) acc[i][j] = z4;

    // ---- prologue: stage tile 0 into buf 0 ----
    if (AF32) {
        float4 a0 = *(const float4*)(agp32);
        float4 a1 = *(const float4*)(agp32 + 4);
        float4 a2 = *(const float4*)(agp32 + 16 * GK);
        float4 a3 = *(const float4*)(agp32 + 16 * GK + 4);
        uint4 wv;
        wv.x = cvtpk2(a0.x, a0.y); wv.y = cvtpk2(a0.z, a0.w);
        wv.z = cvtpk2(a1.x, a1.y); wv.w = cvtpk2(a1.z, a1.w);
        *(uint4*)lwa0 = wv;
        uint4 wv2;
        wv2.x = cvtpk2(a2.x, a2.y); wv2.y = cvtpk2(a2.z, a2.w);
        wv2.z = cvtpk2(a3.x, a3.y); wv2.w = cvtpk2(a3.z, a3.w);
        *(uint4*)(lwa0 + 512) = wv2;
    } else {
        u16* la = &As[0][w * 1024];
        GLDS16(agp, la);
        GLDS16(agp + 16 * GK, la + 512);
    }
    {
        u16* lb = &Bs[0][w * (BN == 128 ? 1024 : 512)];
        if (BN == 128) {
            GLDS16(bgp, lb);
            GLDS16(bgp + 16 * GK, lb + 512);
        } else {
            GLDS16(bgp, lb);
        }
    }
    __syncthreads();

    int cur = 0;
    for (int kt = 0; kt < GK / BK; ++kt) {
        const bool more = (kt + 1 < GK / BK);
        const int ko = (kt + 1) * BK;
        float4 a0, a1, a2, a3;
        if (more) {
            // B: DMA into other buffer; A: load fp32 to regs (or DMA if bf16)
            u16* lb = &Bs[cur ^ 1][w * (BN == 128 ? 1024 : 512)];
            if (BN == 128) {
                GLDS16(bgp + ko, lb);
                GLDS16(bgp + ko + 16 * GK, lb + 512);
            } else {
                GLDS16(bgp + ko, lb);
            }
            if (AF32) {
                a0 = *(const float4*)(agp32 + ko);
                a1 = *(const float4*)(agp32 + ko + 4);
                a2 = *(const float4*)(agp32 + ko + 16 * GK);
                a3 = *(const float4*)(agp32 + ko + 16 * GK + 4);
            } else {
                u16* la = &As[cur ^ 1][w * 1024];
                GLDS16(agp + ko, la);
                GLDS16(agp + ko + 16 * GK, la + 512);
            }
        }
        bf16x8 af[4], bfr[JN];
#pragma unroll
        for (int i = 0; i < 4; ++i)
            af[i] = *(const bf16x8*)&As[cur][(wm * 64 + i * 16 + fr) * BK + fg * 8];
#pragma unroll
        for (int j = 0; j < JN; ++j)
            bfr[j] = *(const bf16x8*)&Bs[cur][(wn * (BN / 2) + j * 16 + fr) * BK + fg * 8];
#pragma unroll
        for (int i = 0; i < 4; ++i)
#pragma unroll
            for (int j = 0; j < JN; ++j)
                acc[i][j] = __builtin_amdgcn_mfma_f32_16x16x32_bf16(af[i], bfr[j], acc[i][j],
                                                                    0, 0, 0);
        if (AF32 && more) {
            // convert + write A(next) into the other buffer (after MFMA so the
            // global loads are covered by compute)
            u16* lw = cur ? lwa0 : lwa1;
            uint4 wv;
            wv.x = cvtpk2(a0.x, a0.y); wv.y = cvtpk2(a0.z, a0.w);
            wv.z = cvtpk2(a1.x, a1.y); wv.w = cvtpk2(a1.z, a1.w);
            *(uint4*)lw = wv;
            uint4 wv2;
            wv2.x = cvtpk2(a2.x, a2.y); wv2.y = cvtpk2(a2.z, a2.w);
            wv2.z = cvtpk2(a3.x, a3.y); wv2.w = cvtpk2(a3.z, a3.w);
            *(uint4*)(lw + 512) = wv2;
        }
        __syncthreads();
        cur ^= 1;
    }

#pragma unroll
    for (int j = 0; j < JN; ++j) {
        const int col = bn0 + wn * (BN / 2) + j * 16 + fr;
        const float bv_ = ga.bias[col];
        if (ga.mode == 2) {
            const int h_ = col >> 6, dk = col & (NDK - 1);
#pragma unroll
            for (int i = 0; i < 4; ++i) {
                const int row0 = bm0 + wm * 64 + i * 16 + fg * 4;
                const int b_ = row0 >> 11, s_ = row0 & (NS - 1);
                uint2 pw;
                pw.x = cvtpk2(acc[i][j][0] + bv_, acc[i][j][1] + bv_);
                pw.y = cvtpk2(acc[i][j][2] + bv_, acc[i][j][3] + bv_);
                *(uint2*)((u16*)ga.out +
                          (((size_t)(b_ * NH + h_)) * NDK + dk) * NS + s_) = pw;
            }
        } else {
#pragma unroll
            for (int i = 0; i < 4; ++i) {
#pragma unroll
                for (int r = 0; r < 4; ++r) {
                    const int row = bm0 + wm * 64 + i * 16 + fg * 4 + r;
                    const float val = acc[i][j][r] + bv_;
                    if (ga.mode == 1) {
                        const int b_ = row >> 11, s_ = row & (NS - 1);
                        const int h_ = col >> 6, dk = col & (NDK - 1);
                        ((bf16_t*)ga.out)[(((size_t)(b_ * NH + h_)) * NS + s_) * NDK + dk] =
                            __float2bfloat16(val);
                    } else {
                        ((float*)ga.out)[(size_t)row * ND + col] = val;
                    }
                }
            }
        }
    }
}

// ---------------------------------------------------------------------------
// Kernel 3: MFMA flash attention — round-12 proven structure (90 us):
// DMA-staged K/V^T dbuf (XOR-swizzled source + same XOR on read), hoisted
// addressing with per-kc base registers (MFMA k-axis is cross-lane, so the
// dk-block selection must be globally uniform — two bases cA/cB), Pt linear
// XOR-swizzled, no-max softmax (exp2), cvt_pk P-pack, ones-MFMA row-sum.
// LDS (40960 B): [0,8192) Kt0, [8192,16384) Kt1, [16384,24576) Vt0,
// [24576,32768) Vt1, [32768,40960) Pt[4][16][64].
// ---------------------------------------------------------------------------
__global__ __launch_bounds__(256) void flash_mfma(const u16* __restrict__ Qh,
                                                  const u16* __restrict__ Kh,
                                                  const u16* __restrict__ VhT,
                                                  const float* __restrict__ comb,
                                                  float* __restrict__ attnOut,
                                                  u16* __restrict__ concatOut) {
    __shared__ __align__(16) char smem[40960];

    const int tid = threadIdx.x;
    const int w = tid >> 6;
    const int lane = tid & 63;
    const int qc = lane & 15;
    const int g = lane >> 4;
    const int bh = blockIdx.y;
    const int b_ = bh >> 4, h_ = bh & 15;
    const int qw = blockIdx.x * 64 + w * 16;

    const size_t bhoff = (size_t)bh * NS * NDK;

    // swizzle decomposition
    const u32 kxl = qc & 3;
    const u32 kx2 = (qc >> 2) & 1;

    // ---- staging (DMA) addresses: wave w stages rows w*16..w*16+15 ----
    const int srow = lane >> 3;          // 0..7 within 8-row chunk
    const int sblk = (lane & 7) ^ srow;  // swizzled 16B block (involution)
    const u16* kgp = Kh + bhoff + (size_t)(w * 16 + srow) * NDK + sblk * 8;
    const u16* vgp = VhT + bhoff + (size_t)(w * 16 + srow) * NS + sblk * 8;
    char* kdst = smem + w * 2048;            // + koff^8192 for buf1
    char* vdst = smem + 16384 + w * 2048;

    // ---- Q fragments (uniform kc pairing — MFMA k-axis is cross-lane) ----
    bf16x8 qf0, qf1;
    {
        const u16* qp = Qh + bhoff + (size_t)(qw + qc) * NDK + g * 8;
        qf0 = *(const bf16x8*)(qp);        // dk 0..31 slice (kc=0)
        qf1 = *(const bf16x8*)(qp + 32);   // dk 32..63 slice (kc=1)
    }

    bf16x8 vones;
#pragma unroll
    for (int j = 0; j < 8; ++j) vones[j] = (short)0x3F80;

    const f32x4 z4 = {0.f, 0.f, 0.f, 0.f};
    f32x4 o[4];
    o[0] = o[1] = o[2] = o[3] = z4;
    f32x4 o_l = z4;

    // ---- per-lane LDS read bases: two per stream (global kc=0 / kc=1) ----
    const u32 cA = kx2 << 6;               // LDS byte offset of global kc=0 block
    const u32 cB = cA ^ 64;                // global kc=1 block
    const u32 laneRC = (u32)qc * 128 + ((g ^ kxl) << 4);
    const char* kb0 = smem + laneRC + cA;             // + koff + ks*2048
    const char* kb1 = smem + laneRC + cB;
    const char* vb0 = smem + 16384 + laneRC + cA;     // + koff + dsub*2048
    const char* vb1 = smem + 16384 + laneRC + cB;
    char* ptrow = smem + 32768 + w * 2048 + qc * 128;
    const char* prd0 = ptrow + ((g ^ kxl) << 4) + cA;
    const char* prd1 = ptrow + ((g ^ kxl) << 4) + cB;
    char* pwb = ptrow + (u32)((g * 8) ^ ((qc & 1) << 4));
    const u32 sxb = (u32)((qc >> 1) & 3) << 5;        // P-write slot XOR (bytes)

    // ---- comb running pointer (g*4 folded in; immediate ks*64B offsets) ----
    const float* cbp = comb + (size_t)(qw + qc) * NS + g * 4;

    // prologue: stage tile 0 into buf 0
    GLDS16(kgp, kdst);
    GLDS16(kgp + 8 * NDK, kdst + 1024);
    GLDS16(vgp, vdst);
    GLDS16(vgp + 8 * NS, vdst + 1024);
    const u16* kgn = kgp + 64 * NDK;  // next-tile running source pointers
    const u16* vgn = vgp + 64;
    __syncthreads();

    u32 koff = 0;
    for (int kt = 0; kt < NS; kt += 64) {
        // stage next tile into the other buffer (overlaps with compute)
        if (kt + 64 < NS) {
            char* kd = kdst + (koff ^ 8192);
            char* vd = vdst + (koff ^ 8192);
            GLDS16(kgn, kd);
            GLDS16(kgn + 8 * NDK, kd + 1024);
            GLDS16(vgn, vd);
            GLDS16(vgn + 8 * NS, vd + 1024);
            kgn += 64 * NDK;
            vgn += 64;
        }

        // ---- QK^T -> S^T [64 key][16 q] ----
        f32x4 s[4];
        s[0] = s[1] = s[2] = s[3] = z4;
#pragma unroll
        for (int ks = 0; ks < 4; ++ks) {
            bf16x8 kf0 = *(const bf16x8*)(kb0 + koff + ks * 2048);
            bf16x8 kf1 = *(const bf16x8*)(kb1 + koff + ks * 2048);
            s[ks] = __builtin_amdgcn_mfma_f32_16x16x32_bf16(kf0, qf0, s[ks], 0, 0, 0);
            s[ks] = __builtin_amdgcn_mfma_f32_16x16x32_bf16(kf1, qf1, s[ks], 0, 0, 0);
        }

        // ---- no-max softmax: p = exp2(s_raw * comb'), masked -> 0 ----
#pragma unroll
        for (int ks = 0; ks < 4; ++ks) {
            float4 c4 = *(const float4*)(cbp + ks * 16);
            const float* cc = (const float*)&c4;
            float p0 = __builtin_amdgcn_exp2f(s[ks][0] * cc[0]);
            float p1 = __builtin_amdgcn_exp2f(s[ks][1] * cc[1]);
            float p2 = __builtin_amdgcn_exp2f(s[ks][2] * cc[2]);
            float p3 = __builtin_amdgcn_exp2f(s[ks][3] * cc[3]);
            p0 = (cc[0] < 0.f) ? 0.f : p0;
            p1 = (cc[1] < 0.f) ? 0.f : p1;
            p2 = (cc[2] < 0.f) ? 0.f : p2;
            p3 = (cc[3] < 0.f) ? 0.f : p3;
            uint2 pw;
            pw.x = cvtpk2(p0, p1);
            pw.y = cvtpk2(p2, p3);
            *(uint2*)(pwb + (((u32)(ks * 32)) ^ sxb)) = pw;
        }
        cbp += 64;

        // ---- ORDER FENCE: P writes (uint2) complete before pf reads (bf16x8)
        // — TBAA-distinct access types through char* smem, enforce explicitly.
        asm volatile("s_waitcnt lgkmcnt(0)" ::: "memory");
        __builtin_amdgcn_sched_barrier(0);

        // ---- PV: O += P * V^T;  o_l += P row-sums ----
        bf16x8 pf0 = *(const bf16x8*)(prd0);
        bf16x8 pf1 = *(const bf16x8*)(prd1);
        o_l = __builtin_amdgcn_mfma_f32_16x16x32_bf16(pf0, vones, o_l, 0, 0, 0);
        o_l = __builtin_amdgcn_mfma_f32_16x16x32_bf16(pf1, vones, o_l, 0, 0, 0);
#pragma unroll
        for (int dsub = 0; dsub < 4; ++dsub) {
            bf16x8 vf0 = *(const bf16x8*)(vb0 + koff + dsub * 2048);
            bf16x8 vf1 = *(const bf16x8*)(vb1 + koff + dsub * 2048);
            o[dsub] = __builtin_amdgcn_mfma_f32_16x16x32_bf16(pf0, vf0, o[dsub], 0, 0, 0);
            o[dsub] = __builtin_amdgcn_mfma_f32_16x16x32_bf16(pf1, vf1, o[dsub], 0, 0, 0);
        }
        __syncthreads();  // drains DMA + protects buffer swap
        koff ^= 8192;
    }

    // ---- normalize + store (attn fp32 [B,H,S,DK], concat bf16 [B,S,D]) ----
    float inv[4];
#pragma unroll
    for (int r = 0; r < 4; ++r) inv[r] = 1.0f / o_l[r];

#pragma unroll
    for (int dsub = 0; dsub < 4; ++dsub) {
#pragma unroll
        for (int r = 0; r < 4; ++r) {
            const float val = o[dsub][r] * inv[r];
            const int qg = qw + g * 4 + r;
            const int d = dsub * 16 + qc;
            attnOut[bhoff + (size_t)qg * NDK + d] = val;
            concatOut[((size_t)b_ * NS + qg) * ND + h_ * NDK + d] = f2bf(val);
        }
    }
}

// ---------------------------------------------------------------------------
extern "C" void kernel_launch(void* const* d_in, const int* in_sizes, int n_in,
                              void* d_out, int out_size, void* d_ws, size_t ws_size,
                              hipStream_t stream) {
    const float* q = (const float*)d_in[0];
    const float* k = (const float*)d_in[1];
    const float* v = (const float*)d_in[2];
    const int* am = (const int*)d_in[3];
    const float* cm = (const float*)d_in[4];
    const float* Wq = (const float*)d_in[5];
    const float* bq = (const float*)d_in[6];
    const float* Wk = (const float*)d_in[7];
    const float* bk = (const float*)d_in[8];
    const float* Wv = (const float*)d_in[9];
    const float* bv = (const float*)d_in[10];
    const float* Wo = (const float*)d_in[11];
    const float* bo = (const float*)d_in[12];

    float* out = (float*)d_out;                    // [B,S,D] fp32
    float* attn_out = out + (size_t)NB * NS * ND;  // [B,H,S,DK] fp32

    char* p = (char*)d_ws;
    float* CB = (float*)p;  p += (size_t)NS * NS * 4;
    u16* Wqb = (u16*)p;     p += (size_t)ND * ND * 2;
    u16* Wkb = (u16*)p;     p += (size_t)ND * ND * 2;
    u16* Wvb = (u16*)p;     p += (size_t)ND * ND * 2;
    u16* Wob = (u16*)p;     p += (size_t)ND * ND * 2;
    u16* Qh = (u16*)p;      p += (size_t)NB * NS * ND * 2;
    u16* Kh = (u16*)p;      p += (size_t)NB * NS * ND * 2;
    u16* VhT = (u16*)p;     p += (size_t)NB * NS * ND * 2;
    u16* CCb = (u16*)p;     p += (size_t)NB * NS * ND * 2;

    PrepArgs pa;
    pa.w_s[0] = Wq;   pa.w_d[0] = Wqb;
    pa.w_s[1] = Wk;   pa.w_d[1] = Wkb;
    pa.w_s[2] = Wv;   pa.w_d[2] = Wvb;
    pa.w_s[3] = Wo;   pa.w_d[3] = Wob;
    pa.am = am;
    pa.cm = cm;
    pa.comb = CB;
    hipLaunchKernelGGL(prep_kernel, dim3(4096, 2), dim3(256), 0, stream, pa);

    MMArgs mq = {(const void*)q, Wqb, bq, (void*)Qh, 1};
    MMArgs mk = {(const void*)k, Wkb, bk, (void*)Kh, 1};
    MMArgs mv = {(const void*)v, Wvb, bv, (void*)VhT, 2};
    hipLaunchKernelGGL((mm_glds<128, 1>), dim3(ND / 128, 4096 / 128, 3), dim3(256), 0, stream,
                       mq, mk, mv);

    hipLaunchKernelGGL(flash_mfma, dim3(NS / 64, NB * NH), dim3(256), 0, stream, Qh, Kh, VhT,
                       CB, attn_out, CCb);

    MMArgs mo = {(const void*)CCb, Wob, bo, (void*)out, 0};
    hipLaunchKernelGGL((mm_glds<64, 0>), dim3(ND / 64, 4096 / 128, 1), dim3(256), 0, stream,
                       mo, mo, mo);
}